// Round 1
// baseline (3189.992 us; speedup 1.0000x reference)
//
#include <hip/hip_runtime.h>

#define NF 8192
#define NBX 4096
#define KN 48

// ---------------------------------------------------------------------------
// geometry: ball->cube + trilinear corner weights for one neighbor
// packs 8 entries of (tap<<16 | bf16(weight)) into g[0..7]
// ---------------------------------------------------------------------------
__device__ __forceinline__ void pn_geom(float rx, float ry, float rz, unsigned* g)
{
    float d2  = rx * rx + ry * ry + rz * rz;
    float om  = 1.0f - d2;
    float win = om * om * om;
    win = fminf(fmaxf(win, 0.0f), 1.0f);

    float rxy2 = rx * rx + ry * ry;
    float rho  = sqrtf(rxy2 + rz * rz + 1e-8f);
    float rxyv = sqrtf(rxy2 + 1e-8f);
    bool  pole = (rxy2 <= 1.25f * rz * rz);
    float s    = pole ? sqrtf(3.0f * rho / (rho + fabsf(rz))) : (rho / rxyv);
    float cx = rx * s, cy = ry * s;
    float sgnz = (rz > 0.0f) ? 1.0f : ((rz < 0.0f) ? -1.0f : 0.0f);
    float cz   = pole ? sgnz * rho : 1.5f * rz;

    float rr   = sqrtf(cx * cx + cy * cy + 1e-8f);
    bool  cond = fabsf(cx) >= fabsf(cy);
    float sx = (cx >= 0.0f) ? 1.0f : -1.0f;
    float sy = (cy >= 0.0f) ? 1.0f : -1.0f;
    float safecx = (fabsf(cx) > 1e-8f) ? cx : 1.0f;
    float safecy = (fabsf(cy) > 1e-8f) ? cy : 1.0f;
    const float C4PI = 1.2732395447351628f;
    float u = cond ? (sx * rr) : (sy * C4PI * rr * atanf(cx / safecy));
    float v = cond ? (sx * C4PI * rr * atanf(cy / safecx)) : (sy * rr);
    if (rho < 1e-6f) { u = 0.0f; v = 0.0f; cz = 0.0f; }

    float tx = fminf(fmaxf((u  * 0.5f + 0.5f) * 3.0f, 0.0f), 3.0f);
    float ty = fminf(fmaxf((v  * 0.5f + 0.5f) * 3.0f, 0.0f), 3.0f);
    float tz = fminf(fmaxf((cz * 0.5f + 0.5f) * 3.0f, 0.0f), 3.0f);
    int ix = (int)floorf(tx); ix = ix < 0 ? 0 : (ix > 2 ? 2 : ix);
    int iy = (int)floorf(ty); iy = iy < 0 ? 0 : (iy > 2 ? 2 : iy);
    int iz = (int)floorf(tz); iz = iz < 0 ? 0 : (iz > 2 ? 2 : iz);
    float fx = tx - (float)ix, fy = ty - (float)iy, fz = tz - (float)iz;
    float wx0 = 1.0f - fx, wy0 = 1.0f - fy, wz0 = 1.0f - fz;

#pragma unroll
    for (int dx = 0; dx < 2; ++dx)
#pragma unroll
        for (int dy = 0; dy < 2; ++dy)
#pragma unroll
            for (int dz = 0; dz < 2; ++dz) {
                float w = (dx ? fx : wx0) * (dy ? fy : wy0) * (dz ? fz : wz0) * win;
                int tap = ((ix + dx) << 4) + ((iy + dy) << 2) + (iz + dz);
                unsigned hb = (__float_as_uint(w) + 0x8000u) >> 16;  // bf16 round
                g[(dx << 2) | (dy << 1) | dz] = ((unsigned)tap << 16) | (hb & 0xffffu);
            }
}

// ---------------------------------------------------------------------------
// prep: vel_new/pos_new, fluid feats, neighbor count, dense d0 branch
// ---------------------------------------------------------------------------
__global__ void __launch_bounds__(256) pn_prep(
    const float* __restrict__ pos, const float* __restrict__ vel,
    const int* __restrict__ nbrf,
    const float* __restrict__ d0w, const float* __restrict__ d0b,
    float* __restrict__ pos_new, float* __restrict__ feats0,
    float* __restrict__ X, float* __restrict__ nfn)
{
    int t = blockIdx.x * 256 + threadIdx.x;
    if (t >= NF) return;
    float vx = vel[t * 3 + 0], vy = vel[t * 3 + 1], vz = vel[t * 3 + 2];
    float vnx = vx, vny = vy - 9.81f * 0.02f, vnz = vz;
    float pnx = pos[t * 3 + 0] + (vx + vnx) * 0.01f;
    float pny = pos[t * 3 + 1] + (vy + vny) * 0.01f;
    float pnz = pos[t * 3 + 2] + (vz + vnz) * 0.01f;
    pos_new[t * 3 + 0] = pnx; pos_new[t * 3 + 1] = pny; pos_new[t * 3 + 2] = pnz;
    feats0[t * 4 + 0] = 1.0f; feats0[t * 4 + 1] = vnx;
    feats0[t * 4 + 2] = vny;  feats0[t * 4 + 3] = vnz;
    int cnt = 0;
    for (int k = 0; k < KN; ++k) cnt += (nbrf[t * KN + k] >= 0) ? 1 : 0;
    nfn[t] = (float)cnt;
    for (int j = 0; j < 32; ++j) {
        float s = d0b[j] + d0w[0 * 32 + j] + vnx * d0w[1 * 32 + j]
                + vny * d0w[2 * 32 + j] + vnz * d0w[3 * 32 + j];
        X[t * 96 + 64 + j] = s;
    }
}

// ---------------------------------------------------------------------------
// pack filt_ext = [conv_w(64,CIN,COUT); dense_w(CIN,COUT)], bias = cb+db
// ---------------------------------------------------------------------------
template <int CIN, int COUT>
__global__ void __launch_bounds__(256) pn_pack(
    const float* __restrict__ cw, const float* __restrict__ dw,
    const float* __restrict__ cb, const float* __restrict__ db,
    float* __restrict__ F, float* __restrict__ B)
{
    int i = blockIdx.x * 256 + threadIdx.x;
    const int nconv = 64 * CIN * COUT, ntot = 65 * CIN * COUT;
    if (i < ntot) F[i] = (i < nconv) ? cw[i] : dw[i - nconv];
    if (i < COUT) B[i] = cb[i] + db[i];
}

// ---------------------------------------------------------------------------
// fused CConv (+optional dense-as-tap-64, relu-on-read, residual, epilogues)
// OUT_MODE: 0 = X-slice, 1 = plain [NF][COUT], 2 = +resid, 3 = final pos/vel
// ---------------------------------------------------------------------------
template <int CIN, int COUT, int ROWS, int TM, int CHUNK, int RELU_IN, int OUT_MODE>
__global__ void __launch_bounds__(256) pn_cconv(
    const float* __restrict__ qpos, const float* __restrict__ ppos,
    const float* __restrict__ feats, const int* __restrict__ nbr,
    const float* __restrict__ filt, const float* __restrict__ bias,
    const float* __restrict__ resid, float* __restrict__ outp,
    const float* __restrict__ pos0, int out_stride, int out_off)
{
    constexpr int NCOL   = TM * COUT;
    constexpr int NACC   = (NCOL + 255) / 256;
    constexpr int NBUILD = TM * CHUNK;
    constexpr int KSPLIT = (256 / NBUILD) > 0 ? (256 / NBUILD) : 1;
    constexpr int KPER   = (KN + KSPLIT - 1) / KSPLIT;

    __shared__ unsigned sG[TM][KN][8];
    __shared__ int      sI[TM][KN];
    __shared__ int      sKN[TM];
    __shared__ float    sA[TM][ROWS][CHUNK];

    const int tid = threadIdx.x;
    const int pt0 = blockIdx.x * TM;

    if (tid < TM) sKN[tid] = KN;
    __syncthreads();

    // phase 0: geometry into LDS (skip masked; padding is front-packed)
    for (int e = tid; e < TM * KN; e += 256) {
        int lp = e / KN, k = e - lp * KN;
        int q  = pt0 + lp;
        int id = nbr[q * KN + k];
        if (id >= 0) {
            sI[lp][k] = id;
            float rx = (ppos[id * 3 + 0] - qpos[q * 3 + 0]) * (1.0f / 0.1125f);
            float ry = (ppos[id * 3 + 1] - qpos[q * 3 + 1]) * (1.0f / 0.1125f);
            float rz = (ppos[id * 3 + 2] - qpos[q * 3 + 2]) * (1.0f / 0.1125f);
            pn_geom(rx, ry, rz, &sG[lp][k][0]);
        } else {
            atomicMin(&sKN[lp], k);
        }
    }

    float acc[NACC];
#pragma unroll
    for (int a = 0; a < NACC; ++a) acc[a] = 0.0f;
    __syncthreads();

    for (int cb0 = 0; cb0 < CIN; cb0 += CHUNK) {
        // zero A-chunk
        for (int i = tid; i < TM * ROWS * CHUNK; i += 256) (&sA[0][0][0])[i] = 0.0f;
        __syncthreads();

        // phase 1: scatter-build A-chunk with LDS atomics (k-range split)
        {
            int kh = tid / NBUILD;
            int r  = tid - kh * NBUILD;
            if (kh < KSPLIT) {
                int lp = r / CHUNK, c = r - lp * CHUNK;
                int kcnt = sKN[lp];
                int k0 = kh * KPER;
                int k1 = kcnt < (k0 + KPER) ? kcnt : (k0 + KPER);
                for (int k = k0; k < k1; ++k) {
                    int   id = sI[lp][k];
                    float f  = feats[id * CIN + cb0 + c];
                    if (RELU_IN) f = fmaxf(f, 0.0f);
#pragma unroll
                    for (int j = 0; j < 8; ++j) {
                        unsigned p = sG[lp][k][j];
                        float w = __uint_as_float((p & 0xffffu) << 16);
                        atomicAdd(&sA[lp][p >> 16][c], w * f);
                    }
                }
                if constexpr (ROWS == 65) {
                    if (kh == 0) {
                        float f = feats[(pt0 + lp) * CIN + cb0 + c];
                        if (RELU_IN) f = fmaxf(f, 0.0f);
                        sA[lp][64][c] = f;
                    }
                }
            }
        }
        __syncthreads();

        // phase 2: acc(pt,d) += A(pt,t,c) * filt(t,c,d)
        if constexpr (NCOL == 512) {
            int d   = tid % COUT;
            int lp0 = tid / COUT;
            constexpr int LPOFF = 256 / COUT;
            const float* fr = filt + (size_t)cb0 * COUT + d;
            float s0 = acc[0], s1 = acc[1];
            for (int t = 0; t < ROWS; ++t) {
#pragma unroll
                for (int c = 0; c < CHUNK; ++c) {
                    float w = fr[c * COUT];
                    s0 += sA[lp0][t][c] * w;
                    s1 += sA[lp0 + LPOFF][t][c] * w;
                }
                fr += CIN * COUT;
            }
            acc[0] = s0; acc[1] = s1;
        } else {
#pragma unroll
            for (int a = 0; a < NACC; ++a) {
                int col = tid + a * 256;
                if (col < NCOL) {
                    int lp = col / COUT, d = col - lp * COUT;
                    float s = acc[a];
                    const float* fr = filt + (size_t)cb0 * COUT + d;
                    for (int t = 0; t < ROWS; ++t) {
#pragma unroll
                        for (int c = 0; c < CHUNK; ++c) s += sA[lp][t][c] * fr[c * COUT];
                        fr += CIN * COUT;
                    }
                    acc[a] = s;
                }
            }
        }
        __syncthreads();
    }

    // epilogue
#pragma unroll
    for (int a = 0; a < NACC; ++a) {
        int col = tid + a * 256;
        if (col < NCOL) {
            int lp = col / COUT, d = col - lp * COUT;
            int q  = pt0 + lp;
            float y = acc[a] + bias[d];
            if constexpr (OUT_MODE == 0) {
                outp[q * out_stride + out_off + d] = y;
            } else if constexpr (OUT_MODE == 1) {
                outp[q * COUT + d] = y;
            } else if constexpr (OUT_MODE == 2) {
                outp[q * COUT + d] = y + resid[q * COUT + d];
            } else {
                float corr = y * (1.0f / 128.0f);
                float pn   = qpos[q * 3 + d];
                float pc   = pn + corr;
                outp[q * 3 + d]          = pc;
                outp[NF * 3 + q * 3 + d] = (pc - pos0[q * 3 + d]) * (1.0f / 0.02f);
            }
        }
    }
}

// ---------------------------------------------------------------------------
// host launcher
// ---------------------------------------------------------------------------
extern "C" void kernel_launch(void* const* d_in, const int* in_sizes, int n_in,
                              void* d_out, int out_size, void* d_ws, size_t ws_size,
                              hipStream_t stream)
{
    (void)in_sizes; (void)n_in; (void)out_size; (void)ws_size;

    const float* pos       = (const float*)d_in[0];
    const float* vel       = (const float*)d_in[1];
    const float* box       = (const float*)d_in[2];
    const float* box_feats = (const float*)d_in[3];
    const int*   nbrf      = (const int*)d_in[4];
    const int*   nbrb      = (const int*)d_in[5];
    const float* cf0_w = (const float*)d_in[6];
    const float* cf0_b = (const float*)d_in[7];
    const float* co0_w = (const float*)d_in[8];
    const float* co0_b = (const float*)d_in[9];
    const float* d0_w  = (const float*)d_in[10];
    const float* d0_b  = (const float*)d_in[11];
    const float* c1_w  = (const float*)d_in[12];
    const float* c1_b  = (const float*)d_in[13];
    const float* d1_w  = (const float*)d_in[14];
    const float* d1_b  = (const float*)d_in[15];
    const float* c2_w  = (const float*)d_in[16];
    const float* c2_b  = (const float*)d_in[17];
    const float* d2_w  = (const float*)d_in[18];
    const float* d2_b  = (const float*)d_in[19];
    const float* c3_w  = (const float*)d_in[20];
    const float* c3_b  = (const float*)d_in[21];
    const float* d3_w  = (const float*)d_in[22];
    const float* d3_b  = (const float*)d_in[23];

    char* ws = (char*)d_ws;
    float* POSNEW = (float*)(ws + 0);         // 8192*3*4   = 98304
    float* FEATS0 = (float*)(ws + 98304);     // 8192*4*4   = 131072
    float* X      = (float*)(ws + 229376);    // 8192*96*4  = 3145728
    float* X1     = (float*)(ws + 3375104);   // 8192*64*4  = 2097152
    float* X2     = (float*)(ws + 5472256);   // 8192*64*4  = 2097152
    float* F1     = (float*)(ws + 7569408);   // 65*96*64*4 = 1597440
    float* F2     = (float*)(ws + 9166848);   // 65*64*64*4 = 1064960
    float* F3     = (float*)(ws + 10231808);  // 65*64*3*4  = 49920
    float* B1     = (float*)(ws + 10281728);
    float* B2     = (float*)(ws + 10281984);
    float* B3     = (float*)(ws + 10282240);

    float* out_f = (float*)d_out;

    pn_pack<96, 64><<<(65 * 96 * 64 + 255) / 256, 256, 0, stream>>>(c1_w, d1_w, c1_b, d1_b, F1, B1);
    pn_pack<64, 64><<<(65 * 64 * 64 + 255) / 256, 256, 0, stream>>>(c2_w, d2_w, c2_b, d2_b, F2, B2);
    pn_pack<64, 3><<<(65 * 64 * 3 + 255) / 256, 256, 0, stream>>>(c3_w, d3_w, c3_b, d3_b, F3, B3);

    pn_prep<<<(NF + 255) / 256, 256, 0, stream>>>(pos, vel, nbrf, d0_w, d0_b,
                                                  POSNEW, FEATS0, X, out_f + NF * 6);

    // cf0: fluid conv 4->32 into X[:,32:64]
    pn_cconv<4, 32, 64, 16, 4, 0, 0><<<NF / 16, 256, 0, stream>>>(
        POSNEW, POSNEW, FEATS0, nbrf, cf0_w, cf0_b, nullptr, X, nullptr, 96, 32);
    // co0: box conv 3->32 into X[:,0:32]
    pn_cconv<3, 32, 64, 16, 3, 0, 0><<<NF / 16, 256, 0, stream>>>(
        POSNEW, box, box_feats, nbrb, co0_w, co0_b, nullptr, X, nullptr, 96, 0);
    // c1: relu(X) 96 -> 64 (conv + dense-as-tap64)
    pn_cconv<96, 64, 65, 8, 16, 1, 1><<<NF / 8, 256, 0, stream>>>(
        POSNEW, POSNEW, X, nbrf, F1, B1, nullptr, X1, nullptr, 0, 0);
    // c2: relu(X1) 64 -> 64, + residual X1
    pn_cconv<64, 64, 65, 8, 16, 1, 2><<<NF / 8, 256, 0, stream>>>(
        POSNEW, POSNEW, X1, nbrf, F2, B2, X1, X2, nullptr, 0, 0);
    // c3: relu(X2) 64 -> 3, final integration epilogue -> d_out
    pn_cconv<64, 3, 65, 8, 16, 1, 3><<<NF / 8, 256, 0, stream>>>(
        POSNEW, POSNEW, X2, nbrf, F3, B3, nullptr, out_f, pos, 0, 0);
}

// Round 3
// 1415.994 us; speedup vs baseline: 2.2528x; 2.2528x over previous
//
#include <hip/hip_runtime.h>

#define NF 8192
#define KN 48

__device__ __forceinline__ unsigned short bf16e(float f) {
    return (unsigned short)((__float_as_uint(f) + 0x8000u) >> 16);
}
__device__ __forceinline__ float bf16lo(unsigned u) { return __uint_as_float(u << 16); }
__device__ __forceinline__ float bf16hi(unsigned u) { return __uint_as_float(u & 0xffff0000u); }
__device__ __forceinline__ float bf16d(unsigned short u) { return __uint_as_float((unsigned)u << 16); }

// ---------------------------------------------------------------------------
// geometry: ball->cube + trilinear corner weights for one neighbor
// packs 8 entries of (tap<<16 | bf16(weight)) into g[0..7]
// ---------------------------------------------------------------------------
__device__ __forceinline__ void pn_geom(float rx, float ry, float rz, unsigned* g)
{
    float d2  = rx * rx + ry * ry + rz * rz;
    float om  = 1.0f - d2;
    float win = om * om * om;
    win = fminf(fmaxf(win, 0.0f), 1.0f);

    float rxy2 = rx * rx + ry * ry;
    float rho  = sqrtf(rxy2 + rz * rz + 1e-8f);
    float rxyv = sqrtf(rxy2 + 1e-8f);
    bool  pole = (rxy2 <= 1.25f * rz * rz);
    float s    = pole ? sqrtf(3.0f * rho / (rho + fabsf(rz))) : (rho / rxyv);
    float cx = rx * s, cy = ry * s;
    float sgnz = (rz > 0.0f) ? 1.0f : ((rz < 0.0f) ? -1.0f : 0.0f);
    float cz   = pole ? sgnz * rho : 1.5f * rz;

    float rr   = sqrtf(cx * cx + cy * cy + 1e-8f);
    bool  cond = fabsf(cx) >= fabsf(cy);
    float sx = (cx >= 0.0f) ? 1.0f : -1.0f;
    float sy = (cy >= 0.0f) ? 1.0f : -1.0f;
    float safecx = (fabsf(cx) > 1e-8f) ? cx : 1.0f;
    float safecy = (fabsf(cy) > 1e-8f) ? cy : 1.0f;
    const float C4PI = 1.2732395447351628f;
    float u = cond ? (sx * rr) : (sy * C4PI * rr * atanf(cx / safecy));
    float v = cond ? (sx * C4PI * rr * atanf(cy / safecx)) : (sy * rr);
    if (rho < 1e-6f) { u = 0.0f; v = 0.0f; cz = 0.0f; }

    float tx = fminf(fmaxf((u  * 0.5f + 0.5f) * 3.0f, 0.0f), 3.0f);
    float ty = fminf(fmaxf((v  * 0.5f + 0.5f) * 3.0f, 0.0f), 3.0f);
    float tz = fminf(fmaxf((cz * 0.5f + 0.5f) * 3.0f, 0.0f), 3.0f);
    int ix = (int)floorf(tx); ix = ix < 0 ? 0 : (ix > 2 ? 2 : ix);
    int iy = (int)floorf(ty); iy = iy < 0 ? 0 : (iy > 2 ? 2 : iy);
    int iz = (int)floorf(tz); iz = iz < 0 ? 0 : (iz > 2 ? 2 : iz);
    float fx = tx - (float)ix, fy = ty - (float)iy, fz = tz - (float)iz;
    float wx0 = 1.0f - fx, wy0 = 1.0f - fy, wz0 = 1.0f - fz;

#pragma unroll
    for (int dx = 0; dx < 2; ++dx)
#pragma unroll
        for (int dy = 0; dy < 2; ++dy)
#pragma unroll
            for (int dz = 0; dz < 2; ++dz) {
                float w = (dx ? fx : wx0) * (dy ? fy : wy0) * (dz ? fz : wz0) * win;
                int tap = ((ix + dx) << 4) + ((iy + dy) << 2) + (iz + dz);
                g[(dx << 2) | (dy << 1) | dz] = ((unsigned)tap << 16) | (unsigned)bf16e(w);
            }
}

// ---------------------------------------------------------------------------
// prep: vel_new/pos_new, fluid feats, neighbor count, dense d0 branch
// ---------------------------------------------------------------------------
__global__ void __launch_bounds__(256) pn_prep(
    const float* __restrict__ pos, const float* __restrict__ vel,
    const int* __restrict__ nbrf,
    const float* __restrict__ d0w, const float* __restrict__ d0b,
    float* __restrict__ pos_new, float* __restrict__ feats0,
    float* __restrict__ X, float* __restrict__ nfn)
{
    int t = blockIdx.x * 256 + threadIdx.x;
    if (t >= NF) return;
    float vx = vel[t * 3 + 0], vy = vel[t * 3 + 1], vz = vel[t * 3 + 2];
    float vnx = vx, vny = vy - 9.81f * 0.02f, vnz = vz;
    float pnx = pos[t * 3 + 0] + (vx + vnx) * 0.01f;
    float pny = pos[t * 3 + 1] + (vy + vny) * 0.01f;
    float pnz = pos[t * 3 + 2] + (vz + vnz) * 0.01f;
    pos_new[t * 3 + 0] = pnx; pos_new[t * 3 + 1] = pny; pos_new[t * 3 + 2] = pnz;
    feats0[t * 4 + 0] = 1.0f; feats0[t * 4 + 1] = vnx;
    feats0[t * 4 + 2] = vny;  feats0[t * 4 + 3] = vnz;
    int cnt = 0;
    for (int k = 0; k < KN; ++k) cnt += (nbrf[t * KN + k] >= 0) ? 1 : 0;
    nfn[t] = (float)cnt;
    for (int j = 0; j < 32; ++j) {
        float s = d0b[j] + d0w[0 * 32 + j] + vnx * d0w[1 * 32 + j]
                + vny * d0w[2 * 32 + j] + vnz * d0w[3 * 32 + j];
        X[t * 96 + 64 + j] = s;
    }
}

// ---------------------------------------------------------------------------
// pack filter to bf16, layout [ROWS][NCH][COUT][CHUNK]; bias = cb (+db if 65)
// row 64 (when ROWS==65) = dense weights (self tap)
// ---------------------------------------------------------------------------
template <int CIN, int COUT, int ROWS, int CHUNK>
__global__ void __launch_bounds__(256) pn_pack(
    const float* __restrict__ cw, const float* __restrict__ dw,
    const float* __restrict__ cb, const float* __restrict__ db,
    unsigned short* __restrict__ FT, float* __restrict__ B)
{
    constexpr int NCH = CIN / CHUNK;
    int i = blockIdx.x * 256 + threadIdx.x;
    int total = ROWS * CIN * COUT;
    if (i < total) {
        int c = i % CHUNK;
        int r = i / CHUNK;
        int d = r % COUT; r /= COUT;
        int ch = r % NCH;
        int t  = r / NCH;
        int cin = ch * CHUNK + c;
        float v;
        if (ROWS == 65 && t == 64) v = dw[(size_t)cin * COUT + d];
        else                       v = cw[((size_t)t * CIN + cin) * COUT + d];
        FT[i] = bf16e(v);
    }
    if (i < COUT) {
        float b = cb[i];
        if constexpr (ROWS == 65) b += db[i];
        B[i] = b;
    }
}

// ---------------------------------------------------------------------------
// fused CConv: CSR tap-gather build (no data atomics) + bf16 filter phase-2
// OUT_MODE: 0 = X-slice, 1 = plain [NF][COUT], 2 = +resid, 3 = final pos/vel
// ---------------------------------------------------------------------------
template <int CIN, int COUT, int ROWS, int TM, int CHUNK, int RELU_IN, int OUT_MODE>
__global__ void __launch_bounds__(256) pn_cconv(
    const float* __restrict__ qpos, const float* __restrict__ ppos,
    const float* __restrict__ feats, const int* __restrict__ nbr,
    const unsigned short* __restrict__ FT, const float* __restrict__ bias,
    const float* __restrict__ resid, float* __restrict__ outp,
    const float* __restrict__ pos0, int out_stride, int out_off)
{
    constexpr int NCH  = CIN / CHUNK;
    constexpr int NCOL = TM * COUT;
    constexpr int NACC = (NCOL + 255) / 256;
    constexpr int CL   = (CHUNK >= 16) ? 16 : ((CHUNK >= 8) ? 8 : 4);
    constexpr int NG   = 256 / CL;
    constexpr int SGB  = TM * KN * 8 * 4;
    constexpr int SFB  = TM * (KN + 1) * CHUNK * 2;
    constexpr int UB   = (SGB > SFB ? SGB : SFB);

    __shared__ int      sI[TM][KN];
    __shared__ int      sKN[TM];
    __shared__ unsigned sEnt[TM][KN * 8];
    __shared__ int      sOff[TM][65];
    __shared__ int      sCur[TM][64];
    __shared__ float    sA[TM][ROWS][CHUNK];
    __shared__ uint4    sU[(UB + 15) / 16];

    unsigned*       sG = (unsigned*)sU;        // [TM][KN][8] during build
    unsigned short* sF = (unsigned short*)sU;  // [TM][KN+1][CHUNK] during chunks

    const int tid = threadIdx.x;
    const int pt0 = blockIdx.x * TM;

    if (tid < TM) sKN[tid] = KN;
    for (int i = tid; i < TM * 64; i += 256) (&sCur[0][0])[i] = 0;
    __syncthreads();

    // phase 0: geometry into sG + per-tap counts
    for (int e = tid; e < TM * KN; e += 256) {
        int lp = e / KN, k = e - lp * KN;
        int q  = pt0 + lp;
        int id = nbr[q * KN + k];
        if (id >= 0) {
            sI[lp][k] = id;
            float rx = (ppos[id * 3 + 0] - qpos[q * 3 + 0]) * (1.0f / 0.1125f);
            float ry = (ppos[id * 3 + 1] - qpos[q * 3 + 1]) * (1.0f / 0.1125f);
            float rz = (ppos[id * 3 + 2] - qpos[q * 3 + 2]) * (1.0f / 0.1125f);
            unsigned g[8];
            pn_geom(rx, ry, rz, g);
#pragma unroll
            for (int j = 0; j < 8; ++j) {
                sG[(lp * KN + k) * 8 + j] = g[j];
                atomicAdd(&sCur[lp][g[j] >> 16], 1);
            }
        } else {
            atomicMin(&sKN[lp], k);
        }
    }
    __syncthreads();

    // prefix-sum per point over 64 taps (one wave per point, lanes = taps)
    {
        int wid = tid >> 6, lane = tid & 63;
        for (int lp = wid; lp < TM; lp += 4) {
            int v = sCur[lp][lane];
            int incl = v;
#pragma unroll
            for (int d = 1; d < 64; d <<= 1) {
                int t = __shfl_up(incl, (unsigned)d, 64);
                if (lane >= d) incl += t;
            }
            int excl = incl - v;
            sOff[lp][lane] = excl;
            sCur[lp][lane] = excl;   // fill cursor
            if (lane == 63) sOff[lp][64] = incl;
        }
    }
    __syncthreads();

    // fill CSR entry lists: (k<<16 | bf16 w)
    for (int e = tid; e < TM * KN; e += 256) {
        int lp = e / KN, k = e - lp * KN;
        if (k < sKN[lp]) {
#pragma unroll
            for (int j = 0; j < 8; ++j) {
                unsigned u  = sG[(lp * KN + k) * 8 + j];
                int tap = (int)(u >> 16);
                int p   = atomicAdd(&sCur[lp][tap], 1);
                sEnt[lp][p] = ((unsigned)k << 16) | (u & 0xffffu);
            }
        }
    }
    __syncthreads();   // sG dead; sF may overwrite

    float acc[NACC];
#pragma unroll
    for (int a = 0; a < NACC; ++a) acc[a] = 0.0f;

    for (int ch = 0; ch < NCH; ++ch) {
        const int cb0 = ch * CHUNK;

        // stage neighbor (+self) feature chunk into LDS as bf16, relu applied
        for (int e = tid; e < TM * (KN + 1); e += 256) {
            int lp = e / (KN + 1), k = e - lp * (KN + 1);
            int id = -1;
            if (k < sKN[lp]) id = sI[lp][k];
            else if (ROWS == 65 && k == KN) id = pt0 + lp;
            if (id >= 0) {
                const float* src = feats + (size_t)id * CIN + cb0;
                unsigned short* dst = sF + (lp * (KN + 1) + k) * CHUNK;
                if constexpr (CHUNK == 16) {
                    const float4* s4 = (const float4*)src;
                    float4 f0 = s4[0], f1 = s4[1], f2 = s4[2], f3 = s4[3];
                    if (RELU_IN) {
                        f0.x=fmaxf(f0.x,0.f); f0.y=fmaxf(f0.y,0.f); f0.z=fmaxf(f0.z,0.f); f0.w=fmaxf(f0.w,0.f);
                        f1.x=fmaxf(f1.x,0.f); f1.y=fmaxf(f1.y,0.f); f1.z=fmaxf(f1.z,0.f); f1.w=fmaxf(f1.w,0.f);
                        f2.x=fmaxf(f2.x,0.f); f2.y=fmaxf(f2.y,0.f); f2.z=fmaxf(f2.z,0.f); f2.w=fmaxf(f2.w,0.f);
                        f3.x=fmaxf(f3.x,0.f); f3.y=fmaxf(f3.y,0.f); f3.z=fmaxf(f3.z,0.f); f3.w=fmaxf(f3.w,0.f);
                    }
                    unsigned p0 = (unsigned)bf16e(f0.x) | ((unsigned)bf16e(f0.y) << 16);
                    unsigned p1 = (unsigned)bf16e(f0.z) | ((unsigned)bf16e(f0.w) << 16);
                    unsigned p2 = (unsigned)bf16e(f1.x) | ((unsigned)bf16e(f1.y) << 16);
                    unsigned p3 = (unsigned)bf16e(f1.z) | ((unsigned)bf16e(f1.w) << 16);
                    unsigned p4 = (unsigned)bf16e(f2.x) | ((unsigned)bf16e(f2.y) << 16);
                    unsigned p5 = (unsigned)bf16e(f2.z) | ((unsigned)bf16e(f2.w) << 16);
                    unsigned p6 = (unsigned)bf16e(f3.x) | ((unsigned)bf16e(f3.y) << 16);
                    unsigned p7 = (unsigned)bf16e(f3.z) | ((unsigned)bf16e(f3.w) << 16);
                    ((uint4*)dst)[0] = make_uint4(p0, p1, p2, p3);
                    ((uint4*)dst)[1] = make_uint4(p4, p5, p6, p7);
                } else {
                    for (int c = 0; c < CHUNK; ++c) {
                        float f = src[c];
                        if (RELU_IN) f = fmaxf(f, 0.0f);
                        dst[c] = bf16e(f);
                    }
                }
            }
        }
        __syncthreads();

        // gather-build A-chunk: thread group (g) x lane (c) owns (tap, c) cells
        {
            int c = tid & (CL - 1);
            int g = tid / CL;
            if (c < CHUNK) {
                for (int lp = 0; lp < TM; ++lp) {
                    for (int t = g; t < ROWS; t += NG) {
                        if (ROWS == 65 && t == ROWS - 1) {
                            sA[lp][ROWS - 1][c] = bf16d(sF[(lp * (KN + 1) + KN) * CHUNK + c]);
                        } else {
                            float s = 0.0f;
                            int o1 = sOff[lp][t + 1];
                            for (int o = sOff[lp][t]; o < o1; ++o) {
                                unsigned u = sEnt[lp][o];
                                s += bf16lo(u) * bf16d(sF[(lp * (KN + 1) + (u >> 16)) * CHUNK + c]);
                            }
                            sA[lp][t][c] = s;
                        }
                    }
                }
            }
        }
        __syncthreads();

        // phase 2: acc(pt,d) += A(pt,t,c) * FT(t,c,d)
        if constexpr (NCOL == 512) {
            const int d   = tid % COUT;
            const int lp0 = tid / COUT;
            constexpr int LPOFF = 256 / COUT;
            float s0 = acc[0], s1 = acc[1];
            if constexpr (CHUNK == 16) {
                for (int t = 0; t < ROWS; ++t) {
                    const uint4* wp = (const uint4*)(FT + (((size_t)t * NCH + ch) * COUT + d) * 16);
                    uint4 w0 = wp[0], w1 = wp[1];
                    const float4* ap = (const float4*)&sA[lp0][t][0];
                    const float4* bp = (const float4*)&sA[lp0 + LPOFF][t][0];
                    float4 a0 = ap[0], a1 = ap[1], a2 = ap[2], a3 = ap[3];
                    float4 b0 = bp[0], b1 = bp[1], b2 = bp[2], b3 = bp[3];
                    float f;
                    f = bf16lo(w0.x); s0 = fmaf(a0.x, f, s0); s1 = fmaf(b0.x, f, s1);
                    f = bf16hi(w0.x); s0 = fmaf(a0.y, f, s0); s1 = fmaf(b0.y, f, s1);
                    f = bf16lo(w0.y); s0 = fmaf(a0.z, f, s0); s1 = fmaf(b0.z, f, s1);
                    f = bf16hi(w0.y); s0 = fmaf(a0.w, f, s0); s1 = fmaf(b0.w, f, s1);
                    f = bf16lo(w0.z); s0 = fmaf(a1.x, f, s0); s1 = fmaf(b1.x, f, s1);
                    f = bf16hi(w0.z); s0 = fmaf(a1.y, f, s0); s1 = fmaf(b1.y, f, s1);
                    f = bf16lo(w0.w); s0 = fmaf(a1.z, f, s0); s1 = fmaf(b1.z, f, s1);
                    f = bf16hi(w0.w); s0 = fmaf(a1.w, f, s0); s1 = fmaf(b1.w, f, s1);
                    f = bf16lo(w1.x); s0 = fmaf(a2.x, f, s0); s1 = fmaf(b2.x, f, s1);
                    f = bf16hi(w1.x); s0 = fmaf(a2.y, f, s0); s1 = fmaf(b2.y, f, s1);
                    f = bf16lo(w1.y); s0 = fmaf(a2.z, f, s0); s1 = fmaf(b2.z, f, s1);
                    f = bf16hi(w1.y); s0 = fmaf(a2.w, f, s0); s1 = fmaf(b2.w, f, s1);
                    f = bf16lo(w1.z); s0 = fmaf(a3.x, f, s0); s1 = fmaf(b3.x, f, s1);
                    f = bf16hi(w1.z); s0 = fmaf(a3.y, f, s0); s1 = fmaf(b3.y, f, s1);
                    f = bf16lo(w1.w); s0 = fmaf(a3.z, f, s0); s1 = fmaf(b3.z, f, s1);
                    f = bf16hi(w1.w); s0 = fmaf(a3.w, f, s0); s1 = fmaf(b3.w, f, s1);
                }
            } else {
                for (int t = 0; t < ROWS; ++t) {
                    const unsigned short* fp = FT + (((size_t)t * NCH + ch) * COUT + d) * CHUNK;
#pragma unroll
                    for (int c = 0; c < CHUNK; ++c) {
                        float f = bf16d(fp[c]);
                        s0 = fmaf(sA[lp0][t][c], f, s0);
                        s1 = fmaf(sA[lp0 + LPOFF][t][c], f, s1);
                    }
                }
            }
            acc[0] = s0; acc[1] = s1;
        } else {
#pragma unroll
            for (int a = 0; a < NACC; ++a) {
                int col = tid + a * 256;
                if (col < NCOL) {
                    int lp = col / COUT, d = col - lp * COUT;
                    float s = acc[a];
                    for (int t = 0; t < ROWS; ++t) {
                        const unsigned short* fp = FT + (((size_t)t * NCH + ch) * COUT + d) * CHUNK;
#pragma unroll
                        for (int c = 0; c < CHUNK; ++c)
                            s = fmaf(sA[lp][t][c], bf16d(fp[c]), s);
                    }
                    acc[a] = s;
                }
            }
        }
        __syncthreads();
    }

    // epilogue
#pragma unroll
    for (int a = 0; a < NACC; ++a) {
        int col = tid + a * 256;
        if (col < NCOL) {
            int lp = col / COUT, d = col - lp * COUT;
            int q  = pt0 + lp;
            float y = acc[a] + bias[d];
            if constexpr (OUT_MODE == 0) {
                outp[q * out_stride + out_off + d] = y;
            } else if constexpr (OUT_MODE == 1) {
                outp[q * COUT + d] = y;
            } else if constexpr (OUT_MODE == 2) {
                outp[q * COUT + d] = y + resid[q * COUT + d];
            } else {
                float corr = y * (1.0f / 128.0f);
                float pn   = qpos[q * 3 + d];
                float pc   = pn + corr;
                outp[q * 3 + d]          = pc;
                outp[NF * 3 + q * 3 + d] = (pc - pos0[q * 3 + d]) * (1.0f / 0.02f);
            }
        }
    }
}

// ---------------------------------------------------------------------------
// host launcher
// ---------------------------------------------------------------------------
extern "C" void kernel_launch(void* const* d_in, const int* in_sizes, int n_in,
                              void* d_out, int out_size, void* d_ws, size_t ws_size,
                              hipStream_t stream)
{
    (void)in_sizes; (void)n_in; (void)out_size; (void)ws_size;

    const float* pos       = (const float*)d_in[0];
    const float* vel       = (const float*)d_in[1];
    const float* box       = (const float*)d_in[2];
    const float* box_feats = (const float*)d_in[3];
    const int*   nbrf      = (const int*)d_in[4];
    const int*   nbrb      = (const int*)d_in[5];
    const float* cf0_w = (const float*)d_in[6];
    const float* cf0_b = (const float*)d_in[7];
    const float* co0_w = (const float*)d_in[8];
    const float* co0_b = (const float*)d_in[9];
    const float* d0_w  = (const float*)d_in[10];
    const float* d0_b  = (const float*)d_in[11];
    const float* c1_w  = (const float*)d_in[12];
    const float* c1_b  = (const float*)d_in[13];
    const float* d1_w  = (const float*)d_in[14];
    const float* d1_b  = (const float*)d_in[15];
    const float* c2_w  = (const float*)d_in[16];
    const float* c2_b  = (const float*)d_in[17];
    const float* d2_w  = (const float*)d_in[18];
    const float* d2_b  = (const float*)d_in[19];
    const float* c3_w  = (const float*)d_in[20];
    const float* c3_b  = (const float*)d_in[21];
    const float* d3_w  = (const float*)d_in[22];
    const float* d3_b  = (const float*)d_in[23];

    char* ws = (char*)d_ws;
    float*          POSNEW = (float*)(ws + 0);         // 98304
    float*          FEATS0 = (float*)(ws + 98304);     // 131072
    float*          X      = (float*)(ws + 229376);    // 8192*96*4
    float*          X1     = (float*)(ws + 3375104);   // 8192*64*4
    float*          X2     = (float*)(ws + 5472256);   // 8192*64*4
    unsigned short* FT1    = (unsigned short*)(ws + 7569408);  // 65*96*64*2 = 798720
    unsigned short* FT2    = (unsigned short*)(ws + 8368128);  // 65*64*64*2 = 532480
    unsigned short* FT3    = (unsigned short*)(ws + 8900608);  // 65*64*3*2  = 24960
    unsigned short* FTf0   = (unsigned short*)(ws + 8925568);  // 64*4*32*2  = 16384
    unsigned short* FTo0   = (unsigned short*)(ws + 8941952);  // 64*3*32*2  = 12288
    float*          B1     = (float*)(ws + 8954240);
    float*          B2     = (float*)(ws + 8954496);
    float*          B3     = (float*)(ws + 8954752);
    float*          Bf0    = (float*)(ws + 8955008);
    float*          Bo0    = (float*)(ws + 8955264);

    float* out_f = (float*)d_out;

    pn_pack<96, 64, 65, 16><<<(65 * 96 * 64 + 255) / 256, 256, 0, stream>>>(c1_w, d1_w, c1_b, d1_b, FT1, B1);
    pn_pack<64, 64, 65, 16><<<(65 * 64 * 64 + 255) / 256, 256, 0, stream>>>(c2_w, d2_w, c2_b, d2_b, FT2, B2);
    pn_pack<64, 3, 65, 16><<<(65 * 64 * 3 + 255) / 256, 256, 0, stream>>>(c3_w, d3_w, c3_b, d3_b, FT3, B3);
    pn_pack<4, 32, 64, 4><<<(64 * 4 * 32 + 255) / 256, 256, 0, stream>>>(cf0_w, nullptr, cf0_b, nullptr, FTf0, Bf0);
    pn_pack<3, 32, 64, 3><<<(64 * 3 * 32 + 255) / 256, 256, 0, stream>>>(co0_w, nullptr, co0_b, nullptr, FTo0, Bo0);

    pn_prep<<<(NF + 255) / 256, 256, 0, stream>>>(pos, vel, nbrf, d0_w, d0_b,
                                                  POSNEW, FEATS0, X, out_f + NF * 6);

    // cf0: fluid conv 4->32 into X[:,32:64]
    pn_cconv<4, 32, 64, 16, 4, 0, 0><<<NF / 16, 256, 0, stream>>>(
        POSNEW, POSNEW, FEATS0, nbrf, FTf0, Bf0, nullptr, X, nullptr, 96, 32);
    // co0: box conv 3->32 into X[:,0:32]
    pn_cconv<3, 32, 64, 16, 3, 0, 0><<<NF / 16, 256, 0, stream>>>(
        POSNEW, box, box_feats, nbrb, FTo0, Bo0, nullptr, X, nullptr, 96, 0);
    // c1: relu(X) 96 -> 64 (conv + dense-as-tap64)
    pn_cconv<96, 64, 65, 8, 16, 1, 1><<<NF / 8, 256, 0, stream>>>(
        POSNEW, POSNEW, X, nbrf, FT1, B1, nullptr, X1, nullptr, 0, 0);
    // c2: relu(X1) 64 -> 64, + residual X1
    pn_cconv<64, 64, 65, 8, 16, 1, 2><<<NF / 8, 256, 0, stream>>>(
        POSNEW, POSNEW, X1, nbrf, FT2, B2, X1, X2, nullptr, 0, 0);
    // c3: relu(X2) 64 -> 3, final integration epilogue -> d_out
    pn_cconv<64, 3, 65, 8, 16, 1, 3><<<NF / 8, 256, 0, stream>>>(
        POSNEW, POSNEW, X2, nbrf, FT3, B3, nullptr, out_f, pos, 0, 0);
}